// Round 1
// baseline (3453.553 us; speedup 1.0000x reference)
//
#include <hip/hip_runtime.h>
#include <math.h>

#define N_NODES 50000
#define E_EDGES 800000
#define EP_EDGES 200000

static inline int idiv(int a, int b) { return (a + b - 1) / b; }

// ---------------- GEMM: C[M,Nn] = A[M,K] @ W[K,Nn] + bias ----------------
__global__ __launch_bounds__(256) void gemm_bias_k(
    const float* __restrict__ A, const float* __restrict__ W,
    const float* __restrict__ bias, float* __restrict__ C,
    int M, int K, int Nn)
{
  __shared__ float As[16][68];
  __shared__ float Bs[16][68];
  const int tid = threadIdx.x;
  const int tx4 = (tid & 15) * 4;
  const int ty4 = (tid >> 4) * 4;
  const int colBase = blockIdx.x * 64;
  const int rowBase = blockIdx.y * 64;
  const int arow = tid >> 2;
  const int ak = (tid & 3) * 4;
  const int bk = tid >> 4;
  const int bc = (tid & 15) * 4;
  float4 acc[4];
  acc[0] = make_float4(0.f, 0.f, 0.f, 0.f);
  acc[1] = acc[0]; acc[2] = acc[0]; acc[3] = acc[0];
  const int grow = rowBase + arow;
  for (int k0 = 0; k0 < K; k0 += 16) {
    float4 av = make_float4(0.f, 0.f, 0.f, 0.f);
    if (grow < M) av = *(const float4*)(A + (size_t)grow * K + (k0 + ak));
    As[ak + 0][arow] = av.x;
    As[ak + 1][arow] = av.y;
    As[ak + 2][arow] = av.z;
    As[ak + 3][arow] = av.w;
    *(float4*)&Bs[bk][bc] = *(const float4*)(W + (size_t)(k0 + bk) * Nn + (colBase + bc));
    __syncthreads();
#pragma unroll
    for (int kk = 0; kk < 16; kk++) {
      float4 a = *(float4*)&As[kk][ty4];
      float4 b = *(float4*)&Bs[kk][tx4];
      acc[0].x += a.x * b.x; acc[0].y += a.x * b.y; acc[0].z += a.x * b.z; acc[0].w += a.x * b.w;
      acc[1].x += a.y * b.x; acc[1].y += a.y * b.y; acc[1].z += a.y * b.z; acc[1].w += a.y * b.w;
      acc[2].x += a.z * b.x; acc[2].y += a.z * b.y; acc[2].z += a.z * b.z; acc[2].w += a.z * b.w;
      acc[3].x += a.w * b.x; acc[3].y += a.w * b.y; acc[3].z += a.w * b.z; acc[3].w += a.w * b.w;
    }
    __syncthreads();
  }
  float4 b4 = *(const float4*)(bias + colBase + tx4);
#pragma unroll
  for (int i = 0; i < 4; i++) {
    int row = rowBase + ty4 + i;
    if (row < M) {
      float4 v = acc[i];
      v.x += b4.x; v.y += b4.y; v.z += b4.z; v.w += b4.w;
      *(float4*)(C + (size_t)row * Nn + (colBase + tx4)) = v;
    }
  }
}

// ------- gather GEMM for predictor: A[e,k] = k<128 ? HA[src[e]] : HT[dst[e]]; K=256, Nn=128, relu -------
__global__ __launch_bounds__(256) void gemm_gather_relu_k(
    const float* __restrict__ HA, const float* __restrict__ HT,
    const int* __restrict__ src, const int* __restrict__ dst,
    const float* __restrict__ W, const float* __restrict__ bias,
    float* __restrict__ C, int M)
{
  __shared__ float As[16][68];
  __shared__ float Bs[16][68];
  const int tid = threadIdx.x;
  const int tx4 = (tid & 15) * 4;
  const int ty4 = (tid >> 4) * 4;
  const int colBase = blockIdx.x * 64;
  const int rowBase = blockIdx.y * 64;
  const int arow = tid >> 2;
  const int ak = (tid & 3) * 4;
  const int bk = tid >> 4;
  const int bc = (tid & 15) * 4;
  float4 acc[4];
  acc[0] = make_float4(0.f, 0.f, 0.f, 0.f);
  acc[1] = acc[0]; acc[2] = acc[0]; acc[3] = acc[0];
  const int grow = rowBase + arow;
  for (int k0 = 0; k0 < 256; k0 += 16) {
    float4 av = make_float4(0.f, 0.f, 0.f, 0.f);
    if (grow < M) {
      int k = k0 + ak;
      int node = (k < 128) ? src[grow] : dst[grow];
      const float* base = (k < 128) ? HA : HT;
      av = *(const float4*)(base + (size_t)node * 128 + (k & 127));
    }
    As[ak + 0][arow] = av.x;
    As[ak + 1][arow] = av.y;
    As[ak + 2][arow] = av.z;
    As[ak + 3][arow] = av.w;
    *(float4*)&Bs[bk][bc] = *(const float4*)(W + (size_t)(k0 + bk) * 128 + (colBase + bc));
    __syncthreads();
#pragma unroll
    for (int kk = 0; kk < 16; kk++) {
      float4 a = *(float4*)&As[kk][ty4];
      float4 b = *(float4*)&Bs[kk][tx4];
      acc[0].x += a.x * b.x; acc[0].y += a.x * b.y; acc[0].z += a.x * b.z; acc[0].w += a.x * b.w;
      acc[1].x += a.y * b.x; acc[1].y += a.y * b.y; acc[1].z += a.y * b.z; acc[1].w += a.y * b.w;
      acc[2].x += a.z * b.x; acc[2].y += a.z * b.y; acc[2].z += a.z * b.z; acc[2].w += a.z * b.w;
      acc[3].x += a.w * b.x; acc[3].y += a.w * b.y; acc[3].z += a.w * b.z; acc[3].w += a.w * b.w;
    }
    __syncthreads();
  }
  float4 b4 = *(const float4*)(bias + colBase + tx4);
#pragma unroll
  for (int i = 0; i < 4; i++) {
    int row = rowBase + ty4 + i;
    if (row < M) {
      float4 v = acc[i];
      v.x = fmaxf(v.x + b4.x, 0.f);
      v.y = fmaxf(v.y + b4.y, 0.f);
      v.z = fmaxf(v.z + b4.z, 0.f);
      v.w = fmaxf(v.w + b4.w, 0.f);
      *(float4*)(C + (size_t)row * 128 + (colBase + tx4)) = v;
    }
  }
}

// ---------------- CSR build ----------------
__global__ __launch_bounds__(256) void hist_k(const int* __restrict__ dst, int* __restrict__ cnt, int e) {
  int i = blockIdx.x * 256 + threadIdx.x;
  if (i < e) atomicAdd(&cnt[dst[i]], 1);
}

__global__ __launch_bounds__(1024) void scan1_k(const int* __restrict__ in, int* __restrict__ excl,
                                                int* __restrict__ bsums, int n) {
  __shared__ int tmp[1024];
  int gid = blockIdx.x * 1024 + threadIdx.x;
  int v = (gid < n) ? in[gid] : 0;
  tmp[threadIdx.x] = v;
  __syncthreads();
  int x = v;
  for (int d = 1; d < 1024; d <<= 1) {
    int y = (threadIdx.x >= d) ? tmp[threadIdx.x - d] : 0;
    __syncthreads();
    x += y;
    tmp[threadIdx.x] = x;
    __syncthreads();
  }
  if (gid < n) excl[gid] = x - v;
  if (threadIdx.x == 1023) bsums[blockIdx.x] = x;
}

__global__ __launch_bounds__(64) void scan2_k(const int* __restrict__ bsums, int* __restrict__ bbase, int nb) {
  int lane = threadIdx.x;
  int v = (lane < nb) ? bsums[lane] : 0;
  int x = v;
  for (int d = 1; d < 64; d <<= 1) {
    int y = __shfl_up(x, d);
    if (lane >= d) x += y;
  }
  if (lane < nb) bbase[lane] = x - v;
}

__global__ __launch_bounds__(1024) void scan3_k(const int* __restrict__ excl, const int* __restrict__ bbase,
                                                int* __restrict__ offsets, int* __restrict__ cursor,
                                                int n, int e) {
  int gid = blockIdx.x * 1024 + threadIdx.x;
  if (gid < n) {
    int o = excl[gid] + bbase[blockIdx.x];
    offsets[gid] = o;
    cursor[gid] = o;
  }
  if (gid == 0) offsets[n] = e;
}

__global__ __launch_bounds__(256) void scatter_k(const int* __restrict__ src, const int* __restrict__ dst,
                                                 int* __restrict__ cursor, int* __restrict__ esrc, int e) {
  int i = blockIdx.x * 256 + threadIdx.x;
  if (i < e) {
    int p = atomicAdd(&cursor[dst[i]], 1);
    esrc[p] = src[i];
  }
}

// -------- GATv2 edge-softmax + aggregate; one wave per destination node --------
__global__ __launch_bounds__(256) void aggregate_k(
    const float* __restrict__ fs, const float* __restrict__ fd,
    const float* __restrict__ attn, const int* __restrict__ offsets,
    const int* __restrict__ esrc, float* __restrict__ zout, int n)
{
  int node = blockIdx.x * 4 + (threadIdx.x >> 6);
  int lane = threadIdx.x & 63;
  if (node >= n) return;
  float2 fd2 = *(const float2*)(fd + (size_t)node * 128 + lane * 2);
  float2 at2 = *(const float2*)(attn + lane * 2);
  int s0 = offsets[node], s1 = offsets[node + 1];
  float acc0 = 0.f, acc1 = 0.f, sacc = 0.f;
  for (int i = s0; i < s1; i++) {
    int src = esrc[i];
    float2 f2 = *(const float2*)(fs + (size_t)src * 128 + lane * 2);
    float t0 = f2.x + fd2.x; t0 = (t0 > 0.f) ? t0 : 0.2f * t0;
    float t1 = f2.y + fd2.y; t1 = (t1 > 0.f) ? t1 : 0.2f * t1;
    float p = t0 * at2.x + t1 * at2.y;
    p += __shfl_xor(p, 1);
    p += __shfl_xor(p, 2);
    p += __shfl_xor(p, 4);
    p += __shfl_xor(p, 8);
    float ex = __expf(p);
    acc0 += ex * f2.x;
    acc1 += ex * f2.y;
    sacc += ex;
  }
  float2 o;
  if (s1 > s0) {
    o.x = fmaxf(acc0 / sacc, 0.f);
    o.y = fmaxf(acc1 / sacc, 0.f);
  } else {
    o.x = 0.f; o.y = 0.f;
  }
  *(float2*)(zout + (size_t)node * 128 + lane * 2) = o;
}

// -------- semantic attention score accumulation: acc += sum_n sum_j tanh(z[n]@Wa + ba)[j]*Wo[j] --------
__global__ __launch_bounds__(128) void satt_k(
    const float* __restrict__ z, const float* __restrict__ Wa,
    const float* __restrict__ ba, const float* __restrict__ Wo,
    float* __restrict__ acc_slot, int n)
{
  __shared__ float WaS[128 * 128];
  int tid = threadIdx.x;
  int lane = tid & 63;
  for (int i = tid; i < 128 * 128; i += 128) WaS[i] = Wa[i];
  float baj = ba[tid];
  float woj = Wo[tid];
  __syncthreads();
  float sum = 0.f;
  for (int row = blockIdx.x; row < n; row += gridDim.x) {
    float2 z2 = *(const float2*)(z + (size_t)row * 128 + lane * 2);
    float acc = baj;
#pragma unroll 16
    for (int k2 = 0; k2 < 64; k2++) {
      float zx = __shfl(z2.x, k2);
      float zy = __shfl(z2.y, k2);
      acc += zx * WaS[(2 * k2) * 128 + tid] + zy * WaS[(2 * k2 + 1) * 128 + tid];
    }
    sum += tanhf(acc) * woj;
  }
  for (int d = 1; d < 64; d <<= 1) sum += __shfl_xor(sum, d);
  __shared__ float wsum[2];
  if (lane == 0) wsum[tid >> 6] = sum;
  __syncthreads();
  if (tid == 0) atomicAdd(acc_slot, wsum[0] + wsum[1]);
}

__global__ void beta_k(const float* __restrict__ w_acc, float* __restrict__ beta, float invn) {
  if (threadIdx.x == 0 && blockIdx.x == 0) {
    float w0 = w_acc[0] * invn, w1 = w_acc[1] * invn;
    float m = fmaxf(w0, w1);
    float e0 = expf(w0 - m), e1 = expf(w1 - m);
    float s = e0 + e1;
    beta[0] = e0 / s; beta[1] = e1 / s;
    float w2 = w_acc[2] * invn, w3 = w_acc[3] * invn;
    float m2 = fmaxf(w2, w3);
    float e2 = expf(w2 - m2), e3 = expf(w3 - m2);
    float s2 = e2 + e3;
    beta[2] = e2 / s2; beta[3] = e3 / s2;
  }
}

__global__ __launch_bounds__(256) void combine_k(const float* __restrict__ za, const float* __restrict__ zb,
                                                 const float* __restrict__ beta2, float* __restrict__ outv, int n4) {
  float b0 = beta2[0], b1 = beta2[1];
  for (int i = blockIdx.x * 256 + threadIdx.x; i < n4; i += gridDim.x * 256) {
    float4 a = ((const float4*)za)[i];
    float4 b = ((const float4*)zb)[i];
    float4 o;
    o.x = a.x * b0 + b.x * b1;
    o.y = a.y * b0 + b.y * b1;
    o.z = a.z * b0 + b.z * b1;
    o.w = a.w * b0 + b.w * b1;
    ((float4*)outv)[i] = o;
  }
}

// -------- predictor stage 2: out[e] = sigmoid(dot(hmid[e], W2) + b2); one wave per edge --------
__global__ __launch_bounds__(256) void gemv_sigmoid_k(const float* __restrict__ hmid, const float* __restrict__ W2,
                                                      const float* __restrict__ b2, float* __restrict__ out, int ne) {
  int wave = (blockIdx.x * 256 + threadIdx.x) >> 6;
  int lane = threadIdx.x & 63;
  if (wave >= ne) return;
  float2 v = *(const float2*)(hmid + (size_t)wave * 128 + lane * 2);
  float2 w = *(const float2*)(W2 + lane * 2);
  float p = v.x * w.x + v.y * w.y;
  p += __shfl_xor(p, 1);
  p += __shfl_xor(p, 2);
  p += __shfl_xor(p, 4);
  p += __shfl_xor(p, 8);
  p += __shfl_xor(p, 16);
  p += __shfl_xor(p, 32);
  if (lane == 0) out[wave] = 1.f / (1.f + expf(-(p + b2[0])));
}

extern "C" void kernel_launch(void* const* d_in, const int* in_sizes, int n_in,
                              void* d_out, int out_size, void* d_ws, size_t ws_size,
                              hipStream_t stream) {
  const float* PE   = (const float*)d_in[0];
  const float* GE   = (const float*)d_in[1];
  const float* W1   = (const float*)d_in[2];
  const float* b1   = (const float*)d_in[3];
  const float* W2   = (const float*)d_in[4];
  const float* b2   = (const float*)d_in[5];
  const float* gWs  = (const float*)d_in[6];
  const float* gbs  = (const float*)d_in[7];
  const float* gWd  = (const float*)d_in[8];
  const float* gbd  = (const float*)d_in[9];
  const float* gattn= (const float*)d_in[10];
  const float* pW1  = (const float*)d_in[11];
  const float* pb1  = (const float*)d_in[12];
  const float* pW2  = (const float*)d_in[13];
  const float* gaW1 = (const float*)d_in[14];
  const float* gab1 = (const float*)d_in[15];
  const float* gaW2 = (const float*)d_in[16];
  const float* prW1 = (const float*)d_in[17];
  const float* prb1 = (const float*)d_in[18];
  const float* prW2 = (const float*)d_in[19];
  const float* prb2 = (const float*)d_in[20];
  const int* e_aa = (const int*)d_in[21];
  const int* e_ta = (const int*)d_in[22];
  const int* e_tt = (const int*)d_in[23];
  const int* e_at = (const int*)d_in[24];
  const int* pos_e = (const int*)d_in[25];
  const int* neg_e = (const int*)d_in[26];
  float* out = (float*)d_out;

  // ---- workspace layout (floats) ----
  float* ws = (float*)d_ws;
  size_t o = 0;
  float* ha = ws + o; o += (size_t)N_NODES * 256;
  float* ht = ws + o; o += (size_t)N_NODES * 256;
  float* fs = ws + o; o += (size_t)N_NODES * 128;
  float* fd = ws + o; o += (size_t)N_NODES * 128;
  float* z[4];
  for (int g = 0; g < 4; g++) { z[g] = ws + o; o += (size_t)N_NODES * 128; }
  float* ha_out = ws + o; o += (size_t)N_NODES * 128;
  float* ht_out = ws + o; o += (size_t)N_NODES * 128;
  float* w_acc = ws + o; o += 8;
  float* beta = ws + o; o += 8;
  int* ib = (int*)(ws + o);
  size_t io = 0;
  int* cnt     = ib + io; io += N_NODES;
  int* excl    = ib + io; io += N_NODES;
  int* bsums   = ib + io; io += 64;
  int* bbase   = ib + io; io += 64;
  int* offsets = ib + io; io += N_NODES + 2;
  int* cursor  = ib + io; io += N_NODES;
  int* esrc    = ib + io; io += E_EDGES;
  float* hmid = fs;  // alias: fs+fd+z0+z1 = 25.6M floats, used only after combine

  const int* eptr[4]   = { e_aa, e_ta, e_tt, e_at };
  const float* hs_g[4] = { ha, ht, ht, ha };
  const float* hd_g[4] = { ha, ha, ht, ht };

  const int SCAN_B = idiv(N_NODES, 1024);  // 49
  dim3 blk256(256), blk1024(1024), blk128(128), blk64(64);

  // node feature GEMMs
  gemm_bias_k<<<dim3(4, idiv(N_NODES, 64)), blk256, 0, stream>>>(PE, W2, b2, ha, N_NODES, 1024, 256);
  gemm_bias_k<<<dim3(4, idiv(N_NODES, 64)), blk256, 0, stream>>>(GE, W1, b1, ht, N_NODES, 512, 256);

  for (int g = 0; g < 4; g++) {
    const int* src = eptr[g];
    const int* dst = eptr[g] + E_EDGES;
    gemm_bias_k<<<dim3(2, idiv(N_NODES, 64)), blk256, 0, stream>>>(
        hs_g[g], gWs + (size_t)g * 256 * 128, gbs + g * 128, fs, N_NODES, 256, 128);
    gemm_bias_k<<<dim3(2, idiv(N_NODES, 64)), blk256, 0, stream>>>(
        hd_g[g], gWd + (size_t)g * 256 * 128, gbd + g * 128, fd, N_NODES, 256, 128);
    hipMemsetAsync(cnt, 0, N_NODES * sizeof(int), stream);
    hist_k<<<idiv(E_EDGES, 256), blk256, 0, stream>>>(dst, cnt, E_EDGES);
    scan1_k<<<SCAN_B, blk1024, 0, stream>>>(cnt, excl, bsums, N_NODES);
    scan2_k<<<1, blk64, 0, stream>>>(bsums, bbase, SCAN_B);
    scan3_k<<<SCAN_B, blk1024, 0, stream>>>(excl, bbase, offsets, cursor, N_NODES, E_EDGES);
    scatter_k<<<idiv(E_EDGES, 256), blk256, 0, stream>>>(src, dst, cursor, esrc, E_EDGES);
    aggregate_k<<<idiv(N_NODES, 4), blk256, 0, stream>>>(
        fs, fd, gattn + (size_t)g * 128, offsets, esrc, z[g], N_NODES);
  }

  // semantic attention
  hipMemsetAsync(w_acc, 0, 4 * sizeof(float), stream);
  satt_k<<<512, blk128, 0, stream>>>(z[0], pW1, pb1, pW2, w_acc + 0, N_NODES);
  satt_k<<<512, blk128, 0, stream>>>(z[1], pW1, pb1, pW2, w_acc + 1, N_NODES);
  satt_k<<<512, blk128, 0, stream>>>(z[2], gaW1, gab1, gaW2, w_acc + 2, N_NODES);
  satt_k<<<512, blk128, 0, stream>>>(z[3], gaW1, gab1, gaW2, w_acc + 3, N_NODES);
  beta_k<<<1, 64, 0, stream>>>(w_acc, beta, 1.0f / (float)N_NODES);

  const int n4 = N_NODES * 128 / 4;
  combine_k<<<2048, blk256, 0, stream>>>(z[0], z[1], beta + 0, ha_out, n4);
  combine_k<<<2048, blk256, 0, stream>>>(z[2], z[3], beta + 2, ht_out, n4);

  // predictor
  gemm_gather_relu_k<<<dim3(2, idiv(EP_EDGES, 64)), blk256, 0, stream>>>(
      ha_out, ht_out, pos_e, pos_e + EP_EDGES, prW1, prb1, hmid, EP_EDGES);
  gemv_sigmoid_k<<<idiv(EP_EDGES, 4), blk256, 0, stream>>>(hmid, prW2, prb2, out, EP_EDGES);
  gemm_gather_relu_k<<<dim3(2, idiv(EP_EDGES, 64)), blk256, 0, stream>>>(
      ha_out, ht_out, neg_e, neg_e + EP_EDGES, prW1, prb1, hmid, EP_EDGES);
  gemv_sigmoid_k<<<idiv(EP_EDGES, 4), blk256, 0, stream>>>(hmid, prW2, prb2, out + EP_EDGES, EP_EDGES);
}

// Round 2
// 1695.764 us; speedup vs baseline: 2.0366x; 2.0366x over previous
//
#include <hip/hip_runtime.h>
#include <math.h>

#define N_NODES 50000
#define E_EDGES 800000
#define EP_EDGES 200000

static inline int idiv(int a, int b) { return (a + b - 1) / b; }

typedef short s16x8 __attribute__((ext_vector_type(8)));
typedef float f32x4 __attribute__((ext_vector_type(4)));

static __device__ __forceinline__ unsigned short f2bf(float f) {
  unsigned int u = __float_as_uint(f);
  u += 0x7FFFu + ((u >> 16) & 1u);
  return (unsigned short)(u >> 16);
}
static __device__ __forceinline__ float bflo(unsigned int u) { return __uint_as_float(u << 16); }
static __device__ __forceinline__ float bfhi(unsigned int u) { return __uint_as_float(u & 0xffff0000u); }

// ---------------- fp32 -> bf16 elementwise (vectorized x4) ----------------
__global__ __launch_bounds__(256) void f2b_k(const float* __restrict__ in,
                                             unsigned short* __restrict__ out, long n4) {
  long i = (long)blockIdx.x * 256 + threadIdx.x;
  long stride = (long)gridDim.x * 256;
  for (; i < n4; i += stride) {
    float4 v = ((const float4*)in)[i];
    ushort4 o;
    o.x = f2bf(v.x); o.y = f2bf(v.y); o.z = f2bf(v.z); o.w = f2bf(v.w);
    ((ushort4*)out)[i] = o;
  }
}

// ---------------- weight transpose+convert: W[K][N] -> Wt[N][K] bf16; K = 1<<kshift ----------------
__global__ __launch_bounds__(256) void wtrans_k(const float* __restrict__ W,
                                                unsigned short* __restrict__ Wt,
                                                int kshift, int total, int Nmat) {
  int b = blockIdx.z;
  const float* Wb = W + (size_t)b * total;
  unsigned short* Wtb = Wt + (size_t)b * total;
  int K = 1 << kshift;
  for (int gid = blockIdx.x * 256 + threadIdx.x; gid < total; gid += gridDim.x * 256) {
    int n = gid >> kshift, k = gid & (K - 1);
    Wtb[gid] = f2bf(Wb[(size_t)k * Nmat + n]);
  }
}

// ---------------- universal bf16 MFMA GEMM: C[M,Nn] = A[M,K] @ Bt^T + bias ----------------
// Bt is [Nn][K] bf16. Tile 128x128, block = 4 waves, each wave 64x64 via 4x4 mfma_16x16x32.
// Gather mode (gsrc!=null): K==256, A row r = concat(GA[gsrc[r]][0:128], GB[gdst[r]][0:128]).
__global__ __launch_bounds__(256) void mfma_gemm_k(
    const unsigned short* __restrict__ A,
    const unsigned short* __restrict__ GA, const unsigned short* __restrict__ GB,
    const int* __restrict__ gsrc, const int* __restrict__ gdst,
    const unsigned short* __restrict__ Bt, const float* __restrict__ bias,
    unsigned short* __restrict__ C, int M, int K, int Nn, int relu)
{
  __shared__ unsigned short As[128 * 32];
  __shared__ unsigned short Bs[128 * 32];
  const int t = threadIdx.x;
  const int rowBase = blockIdx.y * 128;
  const int colBase = blockIdx.x * 128;
  const int srow = t >> 1;            // staged row 0..127
  const int sk = (t & 1) * 16;        // bf16 offset within 32
  const int w = t >> 6, lane = t & 63;
  const int wm = w >> 1, wn = w & 1;
  const int m16 = lane & 15, q = lane >> 4;

  f32x4 acc[4][4];
  const f32x4 zero = {0.f, 0.f, 0.f, 0.f};
#pragma unroll
  for (int i = 0; i < 4; i++)
#pragma unroll
    for (int j = 0; j < 4; j++) acc[i][j] = zero;

  int arow = rowBase + srow;
  if (arow >= M) arow = M - 1;
  int gnode0 = 0, gnode1 = 0;
  const unsigned short* aptr = A ? (A + (size_t)arow * K) : (const unsigned short*)0;
  if (gsrc) { gnode0 = gsrc[arow]; gnode1 = gdst[arow]; }
  const unsigned short* bptr = Bt + (size_t)(colBase + srow) * K;

  for (int k0 = 0; k0 < K; k0 += 32) {
    const unsigned short* asrc;
    if (gsrc) {
      asrc = (k0 < 128) ? (GA + (size_t)gnode0 * 128 + (k0 + sk))
                        : (GB + (size_t)gnode1 * 128 + (k0 - 128 + sk));
    } else {
      asrc = aptr + k0 + sk;
    }
    uint4 a0 = ((const uint4*)asrc)[0];
    uint4 a1 = ((const uint4*)asrc)[1];
    uint4 b0 = ((const uint4*)(bptr + k0 + sk))[0];
    uint4 b1 = ((const uint4*)(bptr + k0 + sk))[1];
    ((uint4*)&As[srow * 32 + sk])[0] = a0;
    ((uint4*)&As[srow * 32 + sk])[1] = a1;
    ((uint4*)&Bs[srow * 32 + sk])[0] = b0;
    ((uint4*)&Bs[srow * 32 + sk])[1] = b1;
    __syncthreads();
    s16x8 af[4], bfr[4];
#pragma unroll
    for (int mi = 0; mi < 4; mi++)
      af[mi] = *(const s16x8*)&As[(wm * 64 + mi * 16 + m16) * 32 + q * 8];
#pragma unroll
    for (int ni = 0; ni < 4; ni++)
      bfr[ni] = *(const s16x8*)&Bs[(wn * 64 + ni * 16 + m16) * 32 + q * 8];
#pragma unroll
    for (int mi = 0; mi < 4; mi++)
#pragma unroll
      for (int ni = 0; ni < 4; ni++)
        acc[mi][ni] = __builtin_amdgcn_mfma_f32_16x16x32_bf16(af[mi], bfr[ni], acc[mi][ni], 0, 0, 0);
    __syncthreads();
  }

#pragma unroll
  for (int ni = 0; ni < 4; ni++) {
    int col = colBase + wn * 64 + ni * 16 + m16;
    float bcol = bias ? bias[col] : 0.f;
#pragma unroll
    for (int mi = 0; mi < 4; mi++) {
#pragma unroll
      for (int r = 0; r < 4; r++) {
        int row = rowBase + wm * 64 + mi * 16 + q * 4 + r;
        if (row < M) {
          float v = acc[mi][ni][r] + bcol;
          if (relu) v = fmaxf(v, 0.f);
          C[(size_t)row * Nn + col] = f2bf(v);
        }
      }
    }
  }
}

// ---------------- semantic attention, MFMA-fused: acc += sum tanh(z@Wa+ba)*Wo ----------------
__global__ __launch_bounds__(256) void satt_mfma_k(
    const unsigned short* __restrict__ z0, const unsigned short* __restrict__ z1,
    const unsigned short* __restrict__ Wat, const float* __restrict__ ba,
    const float* __restrict__ Wo, float* __restrict__ w_acc, int M)
{
  __shared__ unsigned short As[128 * 32];
  __shared__ unsigned short Bs[128 * 32];
  const unsigned short* Z = blockIdx.z ? z1 : z0;
  const int t = threadIdx.x;
  const int rowBase = blockIdx.y * 128;
  const int srow = t >> 1;
  const int sk = (t & 1) * 16;
  const int w = t >> 6, lane = t & 63;
  const int wm = w >> 1, wn = w & 1;
  const int m16 = lane & 15, q = lane >> 4;

  f32x4 acc[4][4];
  const f32x4 zero = {0.f, 0.f, 0.f, 0.f};
#pragma unroll
  for (int i = 0; i < 4; i++)
#pragma unroll
    for (int j = 0; j < 4; j++) acc[i][j] = zero;

  int arow = rowBase + srow;
  if (arow >= M) arow = M - 1;
  const unsigned short* aptr = Z + (size_t)arow * 128;
  const unsigned short* bptr = Wat + (size_t)srow * 128;

  for (int k0 = 0; k0 < 128; k0 += 32) {
    uint4 a0 = ((const uint4*)(aptr + k0 + sk))[0];
    uint4 a1 = ((const uint4*)(aptr + k0 + sk))[1];
    uint4 b0 = ((const uint4*)(bptr + k0 + sk))[0];
    uint4 b1 = ((const uint4*)(bptr + k0 + sk))[1];
    ((uint4*)&As[srow * 32 + sk])[0] = a0;
    ((uint4*)&As[srow * 32 + sk])[1] = a1;
    ((uint4*)&Bs[srow * 32 + sk])[0] = b0;
    ((uint4*)&Bs[srow * 32 + sk])[1] = b1;
    __syncthreads();
    s16x8 af[4], bfr[4];
#pragma unroll
    for (int mi = 0; mi < 4; mi++)
      af[mi] = *(const s16x8*)&As[(wm * 64 + mi * 16 + m16) * 32 + q * 8];
#pragma unroll
    for (int ni = 0; ni < 4; ni++)
      bfr[ni] = *(const s16x8*)&Bs[(wn * 64 + ni * 16 + m16) * 32 + q * 8];
#pragma unroll
    for (int mi = 0; mi < 4; mi++)
#pragma unroll
      for (int ni = 0; ni < 4; ni++)
        acc[mi][ni] = __builtin_amdgcn_mfma_f32_16x16x32_bf16(af[mi], bfr[ni], acc[mi][ni], 0, 0, 0);
    __syncthreads();
  }

  float s = 0.f;
#pragma unroll
  for (int ni = 0; ni < 4; ni++) {
    int col = wn * 64 + ni * 16 + m16;
    float bcol = ba[col], wcol = Wo[col];
#pragma unroll
    for (int mi = 0; mi < 4; mi++) {
#pragma unroll
      for (int r = 0; r < 4; r++) {
        int row = rowBase + wm * 64 + mi * 16 + q * 4 + r;
        if (row < M) s += tanhf(acc[mi][ni][r] + bcol) * wcol;
      }
    }
  }
  for (int d = 1; d < 64; d <<= 1) s += __shfl_xor(s, d);
  __shared__ float red[4];
  if (lane == 0) red[w] = s;
  __syncthreads();
  if (t == 0) atomicAdd(&w_acc[blockIdx.z], red[0] + red[1] + red[2] + red[3]);
}

// ---------------- CSR build ----------------
__global__ __launch_bounds__(256) void hist_k(const int* __restrict__ dst, int* __restrict__ cnt, int e) {
  int i = blockIdx.x * 256 + threadIdx.x;
  if (i < e) atomicAdd(&cnt[dst[i]], 1);
}

__global__ __launch_bounds__(1024) void scan1_k(const int* __restrict__ in, int* __restrict__ excl,
                                                int* __restrict__ bsums, int n) {
  __shared__ int tmp[1024];
  int gid = blockIdx.x * 1024 + threadIdx.x;
  int v = (gid < n) ? in[gid] : 0;
  tmp[threadIdx.x] = v;
  __syncthreads();
  int x = v;
  for (int d = 1; d < 1024; d <<= 1) {
    int y = (threadIdx.x >= d) ? tmp[threadIdx.x - d] : 0;
    __syncthreads();
    x += y;
    tmp[threadIdx.x] = x;
    __syncthreads();
  }
  if (gid < n) excl[gid] = x - v;
  if (threadIdx.x == 1023) bsums[blockIdx.x] = x;
}

__global__ __launch_bounds__(64) void scan2_k(const int* __restrict__ bsums, int* __restrict__ bbase, int nb) {
  int lane = threadIdx.x;
  int v = (lane < nb) ? bsums[lane] : 0;
  int x = v;
  for (int d = 1; d < 64; d <<= 1) {
    int y = __shfl_up(x, d);
    if (lane >= d) x += y;
  }
  if (lane < nb) bbase[lane] = x - v;
}

__global__ __launch_bounds__(1024) void scan3_k(const int* __restrict__ excl, const int* __restrict__ bbase,
                                                int* __restrict__ offsets, int* __restrict__ cursor,
                                                int n, int e) {
  int gid = blockIdx.x * 1024 + threadIdx.x;
  if (gid < n) {
    int o = excl[gid] + bbase[blockIdx.x];
    offsets[gid] = o;
    cursor[gid] = o;
  }
  if (gid == 0) offsets[n] = e;
}

__global__ __launch_bounds__(256) void scatter_k(const int* __restrict__ src, const int* __restrict__ dst,
                                                 int* __restrict__ cursor, int* __restrict__ esrc, int e) {
  int i = blockIdx.x * 256 + threadIdx.x;
  if (i < e) {
    int p = atomicAdd(&cursor[dst[i]], 1);
    esrc[p] = src[i];
  }
}

// -------- GATv2 edge-softmax + aggregate (bf16 features); one wave per destination node --------
__global__ __launch_bounds__(256) void aggregate_k(
    const unsigned short* __restrict__ fs, const unsigned short* __restrict__ fd,
    const float* __restrict__ attn, const int* __restrict__ offsets,
    const int* __restrict__ esrc, unsigned short* __restrict__ zout, int n)
{
  int node = blockIdx.x * 4 + (threadIdx.x >> 6);
  int lane = threadIdx.x & 63;
  if (node >= n) return;
  unsigned int fdu = *(const unsigned int*)(fd + (size_t)node * 128 + lane * 2);
  float fd0 = bflo(fdu), fd1 = bfhi(fdu);
  float2 at2 = *(const float2*)(attn + lane * 2);
  int s0 = offsets[node], s1 = offsets[node + 1];
  float acc0 = 0.f, acc1 = 0.f, sacc = 0.f;
  for (int i = s0; i < s1; i++) {
    int src = esrc[i];
    unsigned int fu = *(const unsigned int*)(fs + (size_t)src * 128 + lane * 2);
    float f0 = bflo(fu), f1 = bfhi(fu);
    float t0 = f0 + fd0; t0 = (t0 > 0.f) ? t0 : 0.2f * t0;
    float t1 = f1 + fd1; t1 = (t1 > 0.f) ? t1 : 0.2f * t1;
    float p = t0 * at2.x + t1 * at2.y;
    p += __shfl_xor(p, 1);
    p += __shfl_xor(p, 2);
    p += __shfl_xor(p, 4);
    p += __shfl_xor(p, 8);
    float ex = __expf(p);
    acc0 += ex * f0;
    acc1 += ex * f1;
    sacc += ex;
  }
  float o0 = 0.f, o1 = 0.f;
  if (s1 > s0) {
    o0 = fmaxf(acc0 / sacc, 0.f);
    o1 = fmaxf(acc1 / sacc, 0.f);
  }
  unsigned int pk = (unsigned int)f2bf(o0) | ((unsigned int)f2bf(o1) << 16);
  *(unsigned int*)(zout + (size_t)node * 128 + lane * 2) = pk;
}

__global__ void beta_k(const float* __restrict__ w_acc, float* __restrict__ beta, float invn) {
  if (threadIdx.x == 0 && blockIdx.x == 0) {
    float w0 = w_acc[0] * invn, w1 = w_acc[1] * invn;
    float m = fmaxf(w0, w1);
    float e0 = expf(w0 - m), e1 = expf(w1 - m);
    float s = e0 + e1;
    beta[0] = e0 / s; beta[1] = e1 / s;
    float w2 = w_acc[2] * invn, w3 = w_acc[3] * invn;
    float m2 = fmaxf(w2, w3);
    float e2 = expf(w2 - m2), e3 = expf(w3 - m2);
    float s2 = e2 + e3;
    beta[2] = e2 / s2; beta[3] = e3 / s2;
  }
}

static __device__ __forceinline__ unsigned int comb2(unsigned int a, unsigned int b, float b0, float b1) {
  float lo = bflo(a) * b0 + bflo(b) * b1;
  float hi = bfhi(a) * b0 + bfhi(b) * b1;
  return (unsigned int)f2bf(lo) | ((unsigned int)f2bf(hi) << 16);
}

__global__ __launch_bounds__(256) void combine_k(const unsigned short* __restrict__ za,
                                                 const unsigned short* __restrict__ zb,
                                                 const float* __restrict__ beta2,
                                                 unsigned short* __restrict__ outv, int n8) {
  float b0 = beta2[0], b1 = beta2[1];
  for (int i = blockIdx.x * 256 + threadIdx.x; i < n8; i += gridDim.x * 256) {
    uint4 a = ((const uint4*)za)[i];
    uint4 b = ((const uint4*)zb)[i];
    uint4 o;
    o.x = comb2(a.x, b.x, b0, b1);
    o.y = comb2(a.y, b.y, b0, b1);
    o.z = comb2(a.z, b.z, b0, b1);
    o.w = comb2(a.w, b.w, b0, b1);
    ((uint4*)outv)[i] = o;
  }
}

// -------- predictor stage 2: out[e] = sigmoid(dot(hmid[e], W2) + b2); one wave per edge --------
__global__ __launch_bounds__(256) void gemv_sigmoid_k(const unsigned short* __restrict__ hmid,
                                                      const float* __restrict__ W2,
                                                      const float* __restrict__ b2,
                                                      float* __restrict__ out, int ne) {
  int wave = (blockIdx.x * 256 + threadIdx.x) >> 6;
  int lane = threadIdx.x & 63;
  if (wave >= ne) return;
  unsigned int v = *(const unsigned int*)(hmid + (size_t)wave * 128 + lane * 2);
  float2 w = *(const float2*)(W2 + lane * 2);
  float p = bflo(v) * w.x + bfhi(v) * w.y;
  p += __shfl_xor(p, 1);
  p += __shfl_xor(p, 2);
  p += __shfl_xor(p, 4);
  p += __shfl_xor(p, 8);
  p += __shfl_xor(p, 16);
  p += __shfl_xor(p, 32);
  if (lane == 0) out[wave] = 1.f / (1.f + expf(-(p + b2[0])));
}

extern "C" void kernel_launch(void* const* d_in, const int* in_sizes, int n_in,
                              void* d_out, int out_size, void* d_ws, size_t ws_size,
                              hipStream_t stream) {
  const float* PE   = (const float*)d_in[0];
  const float* GE   = (const float*)d_in[1];
  const float* W1   = (const float*)d_in[2];
  const float* b1   = (const float*)d_in[3];
  const float* W2   = (const float*)d_in[4];
  const float* b2   = (const float*)d_in[5];
  const float* gWs  = (const float*)d_in[6];
  const float* gbs  = (const float*)d_in[7];
  const float* gWd  = (const float*)d_in[8];
  const float* gbd  = (const float*)d_in[9];
  const float* gattn= (const float*)d_in[10];
  const float* pW1  = (const float*)d_in[11];
  const float* pb1  = (const float*)d_in[12];
  const float* pW2  = (const float*)d_in[13];
  const float* gaW1 = (const float*)d_in[14];
  const float* gab1 = (const float*)d_in[15];
  const float* gaW2 = (const float*)d_in[16];
  const float* prW1 = (const float*)d_in[17];
  const float* prb1 = (const float*)d_in[18];
  const float* prW2 = (const float*)d_in[19];
  const float* prb2 = (const float*)d_in[20];
  const int* e_aa = (const int*)d_in[21];
  const int* e_ta = (const int*)d_in[22];
  const int* e_tt = (const int*)d_in[23];
  const int* e_at = (const int*)d_in[24];
  const int* pos_e = (const int*)d_in[25];
  const int* neg_e = (const int*)d_in[26];
  float* out = (float*)d_out;

  // ---- workspace layout ----
  unsigned short* usws = (unsigned short*)d_ws;
  // region0: PEb (50000*1024) + GEb (50000*512) = 76.8M ushort; later reused for
  // fs/fd/zb[4]/haob/htob (8 * 50000*128 = 51.2M) + hmid (200000*128 = 25.6M) = 76.8M exactly.
  unsigned short* PEb = usws;
  unsigned short* GEb = PEb + (size_t)N_NODES * 1024;
  unsigned short* fs_b = usws;                                   // aliases (used after big GEMMs)
  unsigned short* fd_b = fs_b + (size_t)N_NODES * 128;
  unsigned short* zb0  = fd_b + (size_t)N_NODES * 128;
  unsigned short* zb1  = zb0 + (size_t)N_NODES * 128;
  unsigned short* zb2  = zb1 + (size_t)N_NODES * 128;
  unsigned short* zb3  = zb2 + (size_t)N_NODES * 128;
  unsigned short* haob = zb3 + (size_t)N_NODES * 128;
  unsigned short* htob = haob + (size_t)N_NODES * 128;
  unsigned short* hmid = htob + (size_t)N_NODES * 128;
  unsigned short* zb[4] = { zb0, zb1, zb2, zb3 };

  unsigned short* ha_b = usws + (size_t)N_NODES * 1536;          // 76.8M
  unsigned short* ht_b = ha_b + (size_t)N_NODES * 256;
  unsigned short* wbuf = ht_b + (size_t)N_NODES * 256;
  unsigned short* W2t   = wbuf;                   // 1024*256
  unsigned short* W1t   = W2t + 262144;           // 512*256
  unsigned short* gWst  = W1t + 131072;           // 4*256*128
  unsigned short* gWdt  = gWst + 131072;
  unsigned short* prW1t = gWdt + 131072;          // 256*128
  unsigned short* WaPt  = prW1t + 32768;          // 128*128
  unsigned short* WaGt  = WaPt + 16384;
  float* w_acc = (float*)(WaGt + 16384);
  float* beta  = w_acc + 4;
  int* ib = (int*)(beta + 4);
  size_t io = 0;
  int* cnt     = ib + io; io += N_NODES;
  int* excl    = ib + io; io += N_NODES;
  int* bsums   = ib + io; io += 64;
  int* bbase   = ib + io; io += 64;
  int* offsets = ib + io; io += N_NODES + 2;
  int* cursor  = ib + io; io += N_NODES;
  int* esrc    = ib + io; io += E_EDGES;

  const int* eptr[4] = { e_aa, e_ta, e_tt, e_at };
  const unsigned short* hsb[4] = { ha_b, ht_b, ht_b, ha_b };
  const unsigned short* hdb[4] = { ha_b, ha_b, ht_b, ht_b };

  const int SCAN_B = idiv(N_NODES, 1024);
  dim3 blk256(256), blk1024(1024), blk64(64);
  const int MT = idiv(N_NODES, 128);   // 391 row tiles
  const int ET = idiv(EP_EDGES, 128);  // 1563

  // ---- input conversion + weight transposes ----
  f2b_k<<<4096, blk256, 0, stream>>>(PE, PEb, (long)N_NODES * 1024 / 4);
  f2b_k<<<2048, blk256, 0, stream>>>(GE, GEb, (long)N_NODES * 512 / 4);
  wtrans_k<<<dim3(1024, 1, 1), blk256, 0, stream>>>(W2, W2t, 10, 262144, 256);
  wtrans_k<<<dim3(512, 1, 1),  blk256, 0, stream>>>(W1, W1t, 9, 131072, 256);
  wtrans_k<<<dim3(128, 1, 4),  blk256, 0, stream>>>(gWs, gWst, 8, 32768, 128);
  wtrans_k<<<dim3(128, 1, 4),  blk256, 0, stream>>>(gWd, gWdt, 8, 32768, 128);
  wtrans_k<<<dim3(128, 1, 1),  blk256, 0, stream>>>(prW1, prW1t, 8, 32768, 128);
  wtrans_k<<<dim3(64, 1, 1),   blk256, 0, stream>>>(pW1, WaPt, 7, 16384, 128);
  wtrans_k<<<dim3(64, 1, 1),   blk256, 0, stream>>>(gaW1, WaGt, 7, 16384, 128);

  // ---- input projections (bf16 MFMA) ----
  mfma_gemm_k<<<dim3(2, MT), blk256, 0, stream>>>(PEb, 0, 0, 0, 0, W2t, b2, ha_b, N_NODES, 1024, 256, 0);
  mfma_gemm_k<<<dim3(2, MT), blk256, 0, stream>>>(GEb, 0, 0, 0, 0, W1t, b1, ht_b, N_NODES, 512, 256, 0);

  // ---- 4 metapath GATs ----
  for (int g = 0; g < 4; g++) {
    const int* src = eptr[g];
    const int* dst = eptr[g] + E_EDGES;
    mfma_gemm_k<<<dim3(1, MT), blk256, 0, stream>>>(hsb[g], 0, 0, 0, 0,
        gWst + (size_t)g * 32768, gbs + g * 128, fs_b, N_NODES, 256, 128, 0);
    mfma_gemm_k<<<dim3(1, MT), blk256, 0, stream>>>(hdb[g], 0, 0, 0, 0,
        gWdt + (size_t)g * 32768, gbd + g * 128, fd_b, N_NODES, 256, 128, 0);
    hipMemsetAsync(cnt, 0, N_NODES * sizeof(int), stream);
    hist_k<<<idiv(E_EDGES, 256), blk256, 0, stream>>>(dst, cnt, E_EDGES);
    scan1_k<<<SCAN_B, blk1024, 0, stream>>>(cnt, excl, bsums, N_NODES);
    scan2_k<<<1, blk64, 0, stream>>>(bsums, bbase, SCAN_B);
    scan3_k<<<SCAN_B, blk1024, 0, stream>>>(excl, bbase, offsets, cursor, N_NODES, E_EDGES);
    scatter_k<<<idiv(E_EDGES, 256), blk256, 0, stream>>>(src, dst, cursor, esrc, E_EDGES);
    aggregate_k<<<idiv(N_NODES, 4), blk256, 0, stream>>>(
        fs_b, fd_b, gattn + (size_t)g * 128, offsets, esrc, zb[g], N_NODES);
  }

  // ---- semantic attention ----
  hipMemsetAsync(w_acc, 0, 4 * sizeof(float), stream);
  satt_mfma_k<<<dim3(1, MT, 2), blk256, 0, stream>>>(zb[0], zb[1], WaPt, pb1, pW2, w_acc + 0, N_NODES);
  satt_mfma_k<<<dim3(1, MT, 2), blk256, 0, stream>>>(zb[2], zb[3], WaGt, gab1, gaW2, w_acc + 2, N_NODES);
  beta_k<<<1, 64, 0, stream>>>(w_acc, beta, 1.0f / (float)N_NODES);

  const int n8 = N_NODES * 128 / 8;
  combine_k<<<2048, blk256, 0, stream>>>(zb[0], zb[1], beta + 0, haob, n8);
  combine_k<<<2048, blk256, 0, stream>>>(zb[2], zb[3], beta + 2, htob, n8);

  // ---- predictor ----
  mfma_gemm_k<<<dim3(1, ET), blk256, 0, stream>>>(0, haob, htob, pos_e, pos_e + EP_EDGES,
      prW1t, prb1, hmid, EP_EDGES, 256, 128, 1);
  gemv_sigmoid_k<<<idiv(EP_EDGES, 4), blk256, 0, stream>>>(hmid, prW2, prb2, out, EP_EDGES);
  mfma_gemm_k<<<dim3(1, ET), blk256, 0, stream>>>(0, haob, htob, neg_e, neg_e + EP_EDGES,
      prW1t, prb1, hmid, EP_EDGES, 256, 128, 1);
  gemv_sigmoid_k<<<idiv(EP_EDGES, 4), blk256, 0, stream>>>(hmid, prW2, prb2, out + EP_EDGES, EP_EDGES);
}

// Round 3
// 1560.804 us; speedup vs baseline: 2.2127x; 1.0865x over previous
//
#include <hip/hip_runtime.h>
#include <math.h>

#define N_NODES 50000
#define E_EDGES 800000
#define EP_EDGES 200000
#define NG4 (4 * N_NODES)
#define ETOT (4 * E_EDGES)

static inline int idiv(int a, int b) { return (a + b - 1) / b; }

typedef short s16x8 __attribute__((ext_vector_type(8)));
typedef float f32x4 __attribute__((ext_vector_type(4)));
typedef unsigned short us;

static __device__ __forceinline__ us f2bf(float f) {
  unsigned int u = __float_as_uint(f);
  u += 0x7FFFu + ((u >> 16) & 1u);
  return (us)(u >> 16);
}
static __device__ __forceinline__ float bflo(unsigned int u) { return __uint_as_float(u << 16); }
static __device__ __forceinline__ float bfhi(unsigned int u) { return __uint_as_float(u & 0xffff0000u); }

// ---------------- fused weight transpose+convert: 7 segments via blockIdx.z ----------------
__global__ __launch_bounds__(256) void wtrans_all_k(
    const float* __restrict__ W2, const float* __restrict__ W1,
    const float* __restrict__ gWs, const float* __restrict__ gWd,
    const float* __restrict__ prW1, const float* __restrict__ pW1,
    const float* __restrict__ gaW1,
    us* __restrict__ W2t, us* __restrict__ W1t, us* __restrict__ gWst,
    us* __restrict__ gWdt, us* __restrict__ prW1t, us* __restrict__ WaPt,
    us* __restrict__ WaGt)
{
  const float* src; us* dst; int ks, nsh, total;
  switch (blockIdx.z) {
    case 0: src = W2;   dst = W2t;   ks = 10; nsh = 8; total = 262144; break;
    case 1: src = W1;   dst = W1t;   ks = 9;  nsh = 8; total = 131072; break;
    case 2: src = gWs;  dst = gWst;  ks = 8;  nsh = 7; total = 131072; break;
    case 3: src = gWd;  dst = gWdt;  ks = 8;  nsh = 7; total = 131072; break;
    case 4: src = prW1; dst = prW1t; ks = 8;  nsh = 7; total = 32768;  break;
    case 5: src = pW1;  dst = WaPt;  ks = 7;  nsh = 7; total = 16384;  break;
    default: src = gaW1; dst = WaGt; ks = 7;  nsh = 7; total = 16384;  break;
  }
  int psh = ks + nsh;
  int Km1 = (1 << ks) - 1;
  int pm1 = (1 << psh) - 1;
  for (int gid = blockIdx.x * 256 + threadIdx.x; gid < total; gid += gridDim.x * 256) {
    int mat = gid >> psh;
    int rem = gid & pm1;
    int n = rem >> ks, k = rem & Km1;
    dst[gid] = f2bf(src[((size_t)mat << psh) + ((size_t)k << nsh) + n]);
  }
}

// ------- projection GEMM with fused f32->bf16 A conversion: C[M,256] = bf16(A[M,K]) @ Bt^T + bias -------
// Tile 128 rows x 256 cols (full width); 4 waves as 2x2, each wave 64x128 (4x8 mfma frags).
__global__ __launch_bounds__(256) void proj_gemm_k(
    const float* __restrict__ A, const us* __restrict__ Bt,
    const float* __restrict__ bias, us* __restrict__ C, int M, int K)
{
  __shared__ us As[128 * 40];
  __shared__ us Bs[256 * 40];
  const int t = threadIdx.x;
  const int rowBase = blockIdx.x * 128;
  const int srow = t >> 1, sk = (t & 1) * 16;
  const int w = t >> 6, lane = t & 63;
  const int wm = w >> 1, wn = w & 1;
  const int m16 = lane & 15, q = lane >> 4;

  f32x4 acc[4][8];
  const f32x4 zero = {0.f, 0.f, 0.f, 0.f};
#pragma unroll
  for (int i = 0; i < 4; i++)
#pragma unroll
    for (int j = 0; j < 8; j++) acc[i][j] = zero;

  int arow = rowBase + srow;
  if (arow >= M) arow = M - 1;
  const float* aptr = A + (size_t)arow * K;
  const us* bptr = Bt + (size_t)t * K;

  for (int k0 = 0; k0 < K; k0 += 32) {
    const float* ap = aptr + k0 + sk;
    float4 x0 = ((const float4*)ap)[0];
    float4 x1 = ((const float4*)ap)[1];
    float4 x2 = ((const float4*)ap)[2];
    float4 x3 = ((const float4*)ap)[3];
    uint4 p0, p1;
    p0.x = (unsigned)f2bf(x0.x) | ((unsigned)f2bf(x0.y) << 16);
    p0.y = (unsigned)f2bf(x0.z) | ((unsigned)f2bf(x0.w) << 16);
    p0.z = (unsigned)f2bf(x1.x) | ((unsigned)f2bf(x1.y) << 16);
    p0.w = (unsigned)f2bf(x1.z) | ((unsigned)f2bf(x1.w) << 16);
    p1.x = (unsigned)f2bf(x2.x) | ((unsigned)f2bf(x2.y) << 16);
    p1.y = (unsigned)f2bf(x2.z) | ((unsigned)f2bf(x2.w) << 16);
    p1.z = (unsigned)f2bf(x3.x) | ((unsigned)f2bf(x3.y) << 16);
    p1.w = (unsigned)f2bf(x3.z) | ((unsigned)f2bf(x3.w) << 16);
    uint4 b0 = ((const uint4*)(bptr + k0))[0];
    uint4 b1 = ((const uint4*)(bptr + k0))[1];
    uint4 b2 = ((const uint4*)(bptr + k0))[2];
    uint4 b3 = ((const uint4*)(bptr + k0))[3];
    ((uint4*)&As[srow * 40 + sk])[0] = p0;
    ((uint4*)&As[srow * 40 + sk])[1] = p1;
    ((uint4*)&Bs[t * 40])[0] = b0;
    ((uint4*)&Bs[t * 40])[1] = b1;
    ((uint4*)&Bs[t * 40])[2] = b2;
    ((uint4*)&Bs[t * 40])[3] = b3;
    __syncthreads();
    s16x8 af[4], bfr[8];
#pragma unroll
    for (int mi = 0; mi < 4; mi++)
      af[mi] = *(const s16x8*)&As[(wm * 64 + mi * 16 + m16) * 40 + q * 8];
#pragma unroll
    for (int ni = 0; ni < 8; ni++)
      bfr[ni] = *(const s16x8*)&Bs[(wn * 128 + ni * 16 + m16) * 40 + q * 8];
#pragma unroll
    for (int mi = 0; mi < 4; mi++)
#pragma unroll
      for (int ni = 0; ni < 8; ni++)
        acc[mi][ni] = __builtin_amdgcn_mfma_f32_16x16x32_bf16(af[mi], bfr[ni], acc[mi][ni], 0, 0, 0);
    __syncthreads();
  }

#pragma unroll
  for (int ni = 0; ni < 8; ni++) {
    int col = wn * 128 + ni * 16 + m16;
    float bcol = bias[col];
#pragma unroll
    for (int mi = 0; mi < 4; mi++) {
#pragma unroll
      for (int r = 0; r < 4; r++) {
        int row = rowBase + wm * 64 + mi * 16 + q * 4 + r;
        if (row < M) C[(size_t)row * 256 + col] = f2bf(acc[mi][ni][r] + bcol);
      }
    }
  }
}

// ------- 8 GAT feature GEMMs in one dispatch: z=2g+j (j=0: fs via Ws, j=1: fd via Wd); K=256,Nn=128 -------
__global__ __launch_bounds__(256) void gat_gemm8_k(
    const us* __restrict__ ha, const us* __restrict__ ht,
    const us* __restrict__ gWst, const us* __restrict__ gWdt,
    const float* __restrict__ gbs, const float* __restrict__ gbd,
    us* __restrict__ fs_all, int M)
{
  __shared__ us As[128 * 40];
  __shared__ us Bs[128 * 40];
  const int z = blockIdx.z, g = z >> 1, j = z & 1;
  const us* A = (((j ? 0xC : 0x6) >> g) & 1) ? ht : ha;
  const us* Bt = (j ? gWdt : gWst) + ((size_t)g << 15);
  const float* bias = (j ? gbd : gbs) + g * 128;
  us* C = fs_all + (size_t)z * M * 128;

  const int t = threadIdx.x;
  const int rowBase = blockIdx.y * 128;
  const int srow = t >> 1, sk = (t & 1) * 16;
  const int w = t >> 6, lane = t & 63;
  const int wm = w >> 1, wn = w & 1;
  const int m16 = lane & 15, q = lane >> 4;

  f32x4 acc[4][4];
  const f32x4 zero = {0.f, 0.f, 0.f, 0.f};
#pragma unroll
  for (int i = 0; i < 4; i++)
#pragma unroll
    for (int jj = 0; jj < 4; jj++) acc[i][jj] = zero;

  int arow = rowBase + srow;
  if (arow >= M) arow = M - 1;
  const us* aptr = A + (size_t)arow * 256;
  const us* bptr = Bt + (size_t)srow * 256;

  for (int k0 = 0; k0 < 256; k0 += 32) {
    uint4 a0 = ((const uint4*)(aptr + k0 + sk))[0];
    uint4 a1 = ((const uint4*)(aptr + k0 + sk))[1];
    uint4 b0 = ((const uint4*)(bptr + k0 + sk))[0];
    uint4 b1 = ((const uint4*)(bptr + k0 + sk))[1];
    ((uint4*)&As[srow * 40 + sk])[0] = a0;
    ((uint4*)&As[srow * 40 + sk])[1] = a1;
    ((uint4*)&Bs[srow * 40 + sk])[0] = b0;
    ((uint4*)&Bs[srow * 40 + sk])[1] = b1;
    __syncthreads();
    s16x8 af[4], bfr[4];
#pragma unroll
    for (int mi = 0; mi < 4; mi++)
      af[mi] = *(const s16x8*)&As[(wm * 64 + mi * 16 + m16) * 40 + q * 8];
#pragma unroll
    for (int ni = 0; ni < 4; ni++)
      bfr[ni] = *(const s16x8*)&Bs[(wn * 64 + ni * 16 + m16) * 40 + q * 8];
#pragma unroll
    for (int mi = 0; mi < 4; mi++)
#pragma unroll
      for (int ni = 0; ni < 4; ni++)
        acc[mi][ni] = __builtin_amdgcn_mfma_f32_16x16x32_bf16(af[mi], bfr[ni], acc[mi][ni], 0, 0, 0);
    __syncthreads();
  }

#pragma unroll
  for (int ni = 0; ni < 4; ni++) {
    int col = wn * 64 + ni * 16 + m16;
    float bcol = bias[col];
#pragma unroll
    for (int mi = 0; mi < 4; mi++) {
#pragma unroll
      for (int r = 0; r < 4; r++) {
        int row = rowBase + wm * 64 + mi * 16 + q * 4 + r;
        if (row < M) C[(size_t)row * 128 + col] = f2bf(acc[mi][ni][r] + bcol);
      }
    }
  }
}

// ---------------- CSR build over 4 graphs concatenated ----------------
__global__ __launch_bounds__(256) void hist4_k(
    const int* __restrict__ e_aa, const int* __restrict__ e_ta,
    const int* __restrict__ e_tt, const int* __restrict__ e_at,
    int* __restrict__ cnt4)
{
  int g = blockIdx.z;
  const int* e = g == 0 ? e_aa : g == 1 ? e_ta : g == 2 ? e_tt : e_at;
  const int* dst = e + E_EDGES;
  int i = blockIdx.x * 256 + threadIdx.x;
  if (i < E_EDGES) atomicAdd(&cnt4[g * N_NODES + dst[i]], 1);
}

__global__ __launch_bounds__(1024) void scan1_k(const int* __restrict__ in, int* __restrict__ excl,
                                                int* __restrict__ bsums, int n) {
  __shared__ int tmp[1024];
  int gid = blockIdx.x * 1024 + threadIdx.x;
  int v = (gid < n) ? in[gid] : 0;
  tmp[threadIdx.x] = v;
  __syncthreads();
  int x = v;
  for (int d = 1; d < 1024; d <<= 1) {
    int y = (threadIdx.x >= d) ? tmp[threadIdx.x - d] : 0;
    __syncthreads();
    x += y;
    tmp[threadIdx.x] = x;
    __syncthreads();
  }
  if (gid < n) excl[gid] = x - v;
  if (threadIdx.x == 1023) bsums[blockIdx.x] = x;
}

__global__ __launch_bounds__(256) void scan2_k(const int* __restrict__ bsums, int* __restrict__ bbase, int nb) {
  __shared__ int tmp[256];
  int t = threadIdx.x;
  int v = (t < nb) ? bsums[t] : 0;
  tmp[t] = v;
  __syncthreads();
  int x = v;
  for (int d = 1; d < 256; d <<= 1) {
    int y = (t >= d) ? tmp[t - d] : 0;
    __syncthreads();
    x += y;
    tmp[t] = x;
    __syncthreads();
  }
  if (t < nb) bbase[t] = x - v;
}

__global__ __launch_bounds__(1024) void scan3_k(const int* __restrict__ excl, const int* __restrict__ bbase,
                                                int* __restrict__ offsets, int* __restrict__ cursor,
                                                int n, int e) {
  int gid = blockIdx.x * 1024 + threadIdx.x;
  if (gid < n) {
    int o = excl[gid] + bbase[blockIdx.x];
    offsets[gid] = o;
    cursor[gid] = o;
  }
  if (gid == 0) offsets[n] = e;
}

__global__ __launch_bounds__(256) void scatter4_k(
    const int* __restrict__ e_aa, const int* __restrict__ e_ta,
    const int* __restrict__ e_tt, const int* __restrict__ e_at,
    int* __restrict__ cursor4, int* __restrict__ esrc_all)
{
  int g = blockIdx.z;
  const int* e = g == 0 ? e_aa : g == 1 ? e_ta : g == 2 ? e_tt : e_at;
  const int* src = e;
  const int* dst = e + E_EDGES;
  int i = blockIdx.x * 256 + threadIdx.x;
  if (i < E_EDGES) {
    int p = atomicAdd(&cursor4[g * N_NODES + dst[i]], 1);
    esrc_all[p] = src[i];
  }
}

// -------- GATv2 edge-softmax + aggregate, all 4 graphs (z=graph); one wave per dst node --------
__global__ __launch_bounds__(256) void aggregate4_k(
    const us* __restrict__ fs_all, const float* __restrict__ gattn,
    const int* __restrict__ offs4, const int* __restrict__ esrc_all,
    us* __restrict__ zb_all, int n)
{
  int g = blockIdx.z;
  const us* fs = fs_all + (size_t)(2 * g) * n * 128;
  const us* fd = fs_all + (size_t)(2 * g + 1) * n * 128;
  const float* attn = gattn + g * 128;
  us* zout = zb_all + (size_t)g * n * 128;
  const int* offs = offs4 + (size_t)g * n;

  int node = blockIdx.x * 4 + (threadIdx.x >> 6);
  int lane = threadIdx.x & 63;
  if (node >= n) return;
  unsigned int fdu = *(const unsigned int*)(fd + (size_t)node * 128 + lane * 2);
  float fd0 = bflo(fdu), fd1 = bfhi(fdu);
  float2 at2 = *(const float2*)(attn + lane * 2);
  int s0 = offs[node], s1 = offs[node + 1];
  float acc0 = 0.f, acc1 = 0.f, sacc = 0.f;
  for (int i = s0; i < s1; i++) {
    int src = esrc_all[i];
    unsigned int fu = *(const unsigned int*)(fs + (size_t)src * 128 + lane * 2);
    float f0 = bflo(fu), f1 = bfhi(fu);
    float t0 = f0 + fd0; t0 = (t0 > 0.f) ? t0 : 0.2f * t0;
    float t1 = f1 + fd1; t1 = (t1 > 0.f) ? t1 : 0.2f * t1;
    float p = t0 * at2.x + t1 * at2.y;
    p += __shfl_xor(p, 1);
    p += __shfl_xor(p, 2);
    p += __shfl_xor(p, 4);
    p += __shfl_xor(p, 8);
    float ex = __expf(p);
    acc0 += ex * f0;
    acc1 += ex * f1;
    sacc += ex;
  }
  float o0 = 0.f, o1 = 0.f;
  if (s1 > s0) {
    o0 = fmaxf(acc0 / sacc, 0.f);
    o1 = fmaxf(acc1 / sacc, 0.f);
  }
  unsigned int pk = (unsigned int)f2bf(o0) | ((unsigned int)f2bf(o1) << 16);
  *(unsigned int*)(zout + (size_t)node * 128 + lane * 2) = pk;
}

// ---------------- semantic attention, MFMA-fused ----------------
__global__ __launch_bounds__(256) void satt_mfma_k(
    const us* __restrict__ z0, const us* __restrict__ z1,
    const us* __restrict__ Wat, const float* __restrict__ ba,
    const float* __restrict__ Wo, float* __restrict__ w_acc, int M)
{
  __shared__ us As[128 * 40];
  __shared__ us Bs[128 * 40];
  const us* Z = blockIdx.z ? z1 : z0;
  const int t = threadIdx.x;
  const int rowBase = blockIdx.y * 128;
  const int srow = t >> 1, sk = (t & 1) * 16;
  const int w = t >> 6, lane = t & 63;
  const int wm = w >> 1, wn = w & 1;
  const int m16 = lane & 15, q = lane >> 4;

  f32x4 acc[4][4];
  const f32x4 zero = {0.f, 0.f, 0.f, 0.f};
#pragma unroll
  for (int i = 0; i < 4; i++)
#pragma unroll
    for (int j = 0; j < 4; j++) acc[i][j] = zero;

  int arow = rowBase + srow;
  if (arow >= M) arow = M - 1;
  const us* aptr = Z + (size_t)arow * 128;
  const us* bptr = Wat + (size_t)srow * 128;

  for (int k0 = 0; k0 < 128; k0 += 32) {
    uint4 a0 = ((const uint4*)(aptr + k0 + sk))[0];
    uint4 a1 = ((const uint4*)(aptr + k0 + sk))[1];
    uint4 b0 = ((const uint4*)(bptr + k0 + sk))[0];
    uint4 b1 = ((const uint4*)(bptr + k0 + sk))[1];
    ((uint4*)&As[srow * 40 + sk])[0] = a0;
    ((uint4*)&As[srow * 40 + sk])[1] = a1;
    ((uint4*)&Bs[srow * 40 + sk])[0] = b0;
    ((uint4*)&Bs[srow * 40 + sk])[1] = b1;
    __syncthreads();
    s16x8 af[4], bfr[4];
#pragma unroll
    for (int mi = 0; mi < 4; mi++)
      af[mi] = *(const s16x8*)&As[(wm * 64 + mi * 16 + m16) * 40 + q * 8];
#pragma unroll
    for (int ni = 0; ni < 4; ni++)
      bfr[ni] = *(const s16x8*)&Bs[(wn * 64 + ni * 16 + m16) * 40 + q * 8];
#pragma unroll
    for (int mi = 0; mi < 4; mi++)
#pragma unroll
      for (int ni = 0; ni < 4; ni++)
        acc[mi][ni] = __builtin_amdgcn_mfma_f32_16x16x32_bf16(af[mi], bfr[ni], acc[mi][ni], 0, 0, 0);
    __syncthreads();
  }

  float s = 0.f;
#pragma unroll
  for (int ni = 0; ni < 4; ni++) {
    int col = wn * 64 + ni * 16 + m16;
    float bcol = ba[col], wcol = Wo[col];
#pragma unroll
    for (int mi = 0; mi < 4; mi++) {
#pragma unroll
      for (int r = 0; r < 4; r++) {
        int row = rowBase + wm * 64 + mi * 16 + q * 4 + r;
        if (row < M) s += tanhf(acc[mi][ni][r] + bcol) * wcol;
      }
    }
  }
  for (int d = 1; d < 64; d <<= 1) s += __shfl_xor(s, d);
  __shared__ float red[4];
  if (lane == 0) red[w] = s;
  __syncthreads();
  if (t == 0) atomicAdd(&w_acc[blockIdx.z], red[0] + red[1] + red[2] + red[3]);
}

__global__ void beta_k(const float* __restrict__ w_acc, float* __restrict__ beta, float invn) {
  if (threadIdx.x == 0 && blockIdx.x == 0) {
    float w0 = w_acc[0] * invn, w1 = w_acc[1] * invn;
    float m = fmaxf(w0, w1);
    float e0 = expf(w0 - m), e1 = expf(w1 - m);
    float s = e0 + e1;
    beta[0] = e0 / s; beta[1] = e1 / s;
    float w2 = w_acc[2] * invn, w3 = w_acc[3] * invn;
    float m2 = fmaxf(w2, w3);
    float e2 = expf(w2 - m2), e3 = expf(w3 - m2);
    float s2 = e2 + e3;
    beta[2] = e2 / s2; beta[3] = e3 / s2;
  }
}

static __device__ __forceinline__ unsigned int comb2(unsigned int a, unsigned int b, float b0, float b1) {
  float lo = bflo(a) * b0 + bflo(b) * b1;
  float hi = bfhi(a) * b0 + bfhi(b) * b1;
  return (unsigned int)f2bf(lo) | ((unsigned int)f2bf(hi) << 16);
}

__global__ __launch_bounds__(256) void combine2_k(const us* __restrict__ zb_all,
                                                  const float* __restrict__ beta,
                                                  us* __restrict__ haob, us* __restrict__ htob, int n8) {
  int z = blockIdx.z;
  const us* za = zb_all + (size_t)(2 * z) * N_NODES * 128;
  const us* zbv = zb_all + (size_t)(2 * z + 1) * N_NODES * 128;
  float b0 = beta[2 * z], b1 = beta[2 * z + 1];
  us* outv = z ? htob : haob;
  for (int i = blockIdx.x * 256 + threadIdx.x; i < n8; i += gridDim.x * 256) {
    uint4 a = ((const uint4*)za)[i];
    uint4 b = ((const uint4*)zbv)[i];
    uint4 o;
    o.x = comb2(a.x, b.x, b0, b1);
    o.y = comb2(a.y, b.y, b0, b1);
    o.z = comb2(a.z, b.z, b0, b1);
    o.w = comb2(a.w, b.w, b0, b1);
    ((uint4*)outv)[i] = o;
  }
}

// -------- predictor fully fused: gather-concat GEMM(K=256,N=128) + relu + dot(W2) + sigmoid --------
// z = 0: pos edges, 1: neg edges. Block covers 128 edges; second layer reduced in-block.
__global__ __launch_bounds__(256) void pred_fused_k(
    const us* __restrict__ haob, const us* __restrict__ htob,
    const int* __restrict__ pos_e, const int* __restrict__ neg_e,
    const us* __restrict__ prW1t, const float* __restrict__ prb1,
    const float* __restrict__ prW2, const float* __restrict__ prb2,
    float* __restrict__ out, int M)
{
  __shared__ us As[128 * 40];
  __shared__ us Bs[128 * 40];
  const int z = blockIdx.z;
  const int* pe = z ? neg_e : pos_e;
  float* o = out + (size_t)z * M;

  const int t = threadIdx.x;
  const int rowBase = blockIdx.x * 128;
  const int srow = t >> 1, sk = (t & 1) * 16;
  const int w = t >> 6, lane = t & 63;
  const int wm = w >> 1, wn = w & 1;
  const int m16 = lane & 15, q = lane >> 4;

  f32x4 acc[4][4];
  const f32x4 zero = {0.f, 0.f, 0.f, 0.f};
#pragma unroll
  for (int i = 0; i < 4; i++)
#pragma unroll
    for (int j = 0; j < 4; j++) acc[i][j] = zero;

  int arow = rowBase + srow;
  if (arow >= M) arow = M - 1;
  const int srcn = pe[arow];
  const int dstn = pe[M + arow];
  const us* bptr = prW1t + (size_t)srow * 256;

  for (int k0 = 0; k0 < 256; k0 += 32) {
    const us* asrc = (k0 < 128) ? (haob + (size_t)srcn * 128 + k0 + sk)
                                : (htob + (size_t)dstn * 128 + (k0 - 128) + sk);
    uint4 a0 = ((const uint4*)asrc)[0];
    uint4 a1 = ((const uint4*)asrc)[1];
    uint4 b0 = ((const uint4*)(bptr + k0 + sk))[0];
    uint4 b1 = ((const uint4*)(bptr + k0 + sk))[1];
    ((uint4*)&As[srow * 40 + sk])[0] = a0;
    ((uint4*)&As[srow * 40 + sk])[1] = a1;
    ((uint4*)&Bs[srow * 40 + sk])[0] = b0;
    ((uint4*)&Bs[srow * 40 + sk])[1] = b1;
    __syncthreads();
    s16x8 af[4], bfr[4];
#pragma unroll
    for (int mi = 0; mi < 4; mi++)
      af[mi] = *(const s16x8*)&As[(wm * 64 + mi * 16 + m16) * 40 + q * 8];
#pragma unroll
    for (int ni = 0; ni < 4; ni++)
      bfr[ni] = *(const s16x8*)&Bs[(wn * 64 + ni * 16 + m16) * 40 + q * 8];
#pragma unroll
    for (int mi = 0; mi < 4; mi++)
#pragma unroll
      for (int ni = 0; ni < 4; ni++)
        acc[mi][ni] = __builtin_amdgcn_mfma_f32_16x16x32_bf16(af[mi], bfr[ni], acc[mi][ni], 0, 0, 0);
    __syncthreads();
  }

  // layer 2: per-row dot with prW2 after relu(+prb1)
  float* rsum = (float*)As;
  if (t < 128) rsum[t] = 0.f;
  __syncthreads();
  float bcol[4], w2c[4];
#pragma unroll
  for (int ni = 0; ni < 4; ni++) {
    int col = wn * 64 + ni * 16 + m16;
    bcol[ni] = prb1[col];
    w2c[ni] = prW2[col];
  }
#pragma unroll
  for (int mi = 0; mi < 4; mi++) {
#pragma unroll
    for (int r = 0; r < 4; r++) {
      float s = 0.f;
#pragma unroll
      for (int ni = 0; ni < 4; ni++)
        s += fmaxf(acc[mi][ni][r] + bcol[ni], 0.f) * w2c[ni];
      s += __shfl_xor(s, 1);
      s += __shfl_xor(s, 2);
      s += __shfl_xor(s, 4);
      s += __shfl_xor(s, 8);
      if (m16 == 0) atomicAdd(&rsum[wm * 64 + mi * 16 + q * 4 + r], s);
    }
  }
  __syncthreads();
  if (t < 128) {
    int row = rowBase + t;
    if (row < M) o[row] = 1.f / (1.f + expf(-(rsum[t] + prb2[0])));
  }
}

extern "C" void kernel_launch(void* const* d_in, const int* in_sizes, int n_in,
                              void* d_out, int out_size, void* d_ws, size_t ws_size,
                              hipStream_t stream) {
  const float* PE   = (const float*)d_in[0];
  const float* GE   = (const float*)d_in[1];
  const float* W1   = (const float*)d_in[2];
  const float* b1   = (const float*)d_in[3];
  const float* W2   = (const float*)d_in[4];
  const float* b2   = (const float*)d_in[5];
  const float* gWs  = (const float*)d_in[6];
  const float* gbs  = (const float*)d_in[7];
  const float* gWd  = (const float*)d_in[8];
  const float* gbd  = (const float*)d_in[9];
  const float* gattn= (const float*)d_in[10];
  const float* pW1  = (const float*)d_in[11];
  const float* pb1  = (const float*)d_in[12];
  const float* pW2  = (const float*)d_in[13];
  const float* gaW1 = (const float*)d_in[14];
  const float* gab1 = (const float*)d_in[15];
  const float* gaW2 = (const float*)d_in[16];
  const float* prW1 = (const float*)d_in[17];
  const float* prb1 = (const float*)d_in[18];
  const float* prW2 = (const float*)d_in[19];
  const float* prb2 = (const float*)d_in[20];
  const int* e_aa = (const int*)d_in[21];
  const int* e_ta = (const int*)d_in[22];
  const int* e_tt = (const int*)d_in[23];
  const int* e_at = (const int*)d_in[24];
  const int* pos_e = (const int*)d_in[25];
  const int* neg_e = (const int*)d_in[26];
  float* out = (float*)d_out;

  // ---- workspace layout ----
  us* usws = (us*)d_ws;
  size_t o = 0;
  us* ha_b   = usws + o; o += (size_t)N_NODES * 256;   // 12.8M
  us* ht_b   = usws + o; o += (size_t)N_NODES * 256;
  us* fs_all = usws + o; o += (size_t)8 * N_NODES * 128; // 51.2M
  us* zb_all = usws + o; o += (size_t)4 * N_NODES * 128; // 25.6M
  us* haob   = usws + o; o += (size_t)N_NODES * 128;
  us* htob   = usws + o; o += (size_t)N_NODES * 128;
  us* W2t    = usws + o; o += 262144;
  us* W1t    = usws + o; o += 131072;
  us* gWst   = usws + o; o += 131072;
  us* gWdt   = usws + o; o += 131072;
  us* prW1t  = usws + o; o += 32768;
  us* WaPt   = usws + o; o += 16384;
  us* WaGt   = usws + o; o += 16384;
  float* w_acc = (float*)(usws + o); o += 16;
  float* beta  = w_acc + 4;
  int* ib = (int*)(usws + o);
  size_t io = 0;
  int* cnt4    = ib + io; io += NG4;
  int* excl    = ib + io; io += NG4;
  int* bsums   = ib + io; io += 256;
  int* bbase   = ib + io; io += 256;
  int* offs4   = ib + io; io += NG4 + 4;
  int* cursor4 = ib + io; io += NG4;
  int* esrc    = ib + io; io += ETOT;

  const int SCAN_B = idiv(NG4, 1024);  // 196
  dim3 blk256(256), blk1024(1024);
  const int MT = idiv(N_NODES, 128);   // 391
  const int ET = idiv(EP_EDGES, 128);  // 1563

  // 1) weights
  wtrans_all_k<<<dim3(64, 1, 7), blk256, 0, stream>>>(
      W2, W1, gWs, gWd, prW1, pW1, gaW1, W2t, W1t, gWst, gWdt, prW1t, WaPt, WaGt);

  // 2-3) input projections (fused fp32->bf16, full-width 256-col tile)
  proj_gemm_k<<<dim3(MT), blk256, 0, stream>>>(PE, W2t, b2, ha_b, N_NODES, 1024);
  proj_gemm_k<<<dim3(MT), blk256, 0, stream>>>(GE, W1t, b1, ht_b, N_NODES, 512);

  // 4) all 8 GAT feature GEMMs
  gat_gemm8_k<<<dim3(1, MT, 8), blk256, 0, stream>>>(ha_b, ht_b, gWst, gWdt, gbs, gbd, fs_all, N_NODES);

  // 5-10) CSR build for all 4 graphs at once
  hipMemsetAsync(cnt4, 0, NG4 * sizeof(int), stream);
  hist4_k<<<dim3(idiv(E_EDGES, 256), 1, 4), blk256, 0, stream>>>(e_aa, e_ta, e_tt, e_at, cnt4);
  scan1_k<<<SCAN_B, blk1024, 0, stream>>>(cnt4, excl, bsums, NG4);
  scan2_k<<<1, blk256, 0, stream>>>(bsums, bbase, SCAN_B);
  scan3_k<<<SCAN_B, blk1024, 0, stream>>>(excl, bbase, offs4, cursor4, NG4, ETOT);
  scatter4_k<<<dim3(idiv(E_EDGES, 256), 1, 4), blk256, 0, stream>>>(e_aa, e_ta, e_tt, e_at, cursor4, esrc);

  // 11) all 4 edge-softmax aggregations
  aggregate4_k<<<dim3(idiv(N_NODES, 4), 1, 4), blk256, 0, stream>>>(fs_all, gattn, offs4, esrc, zb_all, N_NODES);

  // 12-13) semantic attention
  hipMemsetAsync(w_acc, 0, 4 * sizeof(float), stream);
  satt_mfma_k<<<dim3(1, MT, 2), blk256, 0, stream>>>(
      zb_all, zb_all + (size_t)N_NODES * 128, WaPt, pb1, pW2, w_acc + 0, N_NODES);
  satt_mfma_k<<<dim3(1, MT, 2), blk256, 0, stream>>>(
      zb_all + (size_t)2 * N_NODES * 128, zb_all + (size_t)3 * N_NODES * 128, WaGt, gab1, gaW2, w_acc + 2, N_NODES);
  beta_k<<<1, 64, 0, stream>>>(w_acc, beta, 1.0f / (float)N_NODES);

  // 14) combine both groups
  combine2_k<<<dim3(2048, 1, 2), blk256, 0, stream>>>(zb_all, beta, haob, htob, N_NODES * 128 / 8);

  // 15) fully fused predictor (pos+neg)
  pred_fused_k<<<dim3(ET, 1, 2), blk256, 0, stream>>>(
      haob, htob, pos_e, neg_e, prW1t, prb1, prW2, prb2, out, EP_EDGES);
}